// Round 2
// baseline (4397.746 us; speedup 1.0000x reference)
//
#include <hip/hip_runtime.h>
#include <hip/hip_fp16.h>

#define N_ 32
#define C_ 512
#define P_ 1024
#define S_ 2048
#define TPW 8      // p-values per block in K1
#define KC 32      // k-chunk (C) staged per iteration
#define SC 64      // s-chunk staged per iteration
#define KCAND 48   // candidates kept per (n,p); sel-margin ~7e-3 >> fp32 noise 6e-5

// ---------------- K1: scores + top-K select + np-fp32-exact rescore ----------------
__global__ __launch_bounds__(256) void k1_score_select(
    const float* __restrict__ x, const float* __restrict__ cb,
    float* __restrict__ out, double* __restrict__ cb_partial) {
  __shared__ float dval[TPW][KCAND];      // 1536 B  (np-fp32 d values of candidates)
  __shared__ float x2f[TPW];              // 32 B    (np-fp32 sequential x2)
  __shared__ double redd[4];              // 32 B
  __shared__ float x_t[TPW][C_ + 4];      // 16512 B
  __shared__ float cb_t[SC][KC + 4];      // 9216 B
  __shared__ int cand_s[TPW][KCAND];      // 1536 B
  __shared__ _Float16 sc[S_][TPW];        // 32768 B   (total 61632 B < 64 KB)

  const int tid = threadIdx.x;
  const int bx = blockIdx.x;
  const int n = bx >> 7;             // 128 p-tiles per n
  const int p0 = (bx & 127) * TPW;

  // ---- load x tile, transposed to [p][c] ----
  const float* xn = x + (size_t)n * C_ * P_ + p0;
#pragma unroll
  for (int q = 0; q < 16; ++q) {
    int e = tid + 256 * q;
    int c = e >> 3, j = e & 7;
    x_t[j][c] = xn[(size_t)c * P_ + j];
  }
  __syncthreads();

  // ---- x2 per p: numpy axis-1 (outer-axis) reduce = STRICT sequential fp32 over c,
  //      product rounded then add rounded, no FMA ----
  if (tid < TPW) {
    float acc = 0.f;
    for (int c = 0; c < C_; ++c)
      acc = __fadd_rn(acc, __fmul_rn(x_t[tid][c], x_t[tid][c]));
    x2f[tid] = acc;
  }
  // (next loop's leading __syncthreads() orders these writes before any read)

  // ---- approximate scores: sc[s][j] = xc (select by MAX xc <=> min distance).
  //      Fast FMA path — selection only; exactness not needed here. ----
  const int j = tid & 7;
  const int sg = tid >> 3;  // 0..31
  for (int s0 = 0; s0 < S_; s0 += SC) {
    float acc0 = 0.f, acc1 = 0.f;
    for (int k0 = 0; k0 < C_; k0 += KC) {
      __syncthreads();  // protect cb_t (also orders x2f writes on 1st iter)
#pragma unroll
      for (int q = 0; q < 8; ++q) {
        int e = tid + 256 * q;
        int i = e >> 5, cc = e & 31;
        cb_t[i][cc] = cb[(size_t)(s0 + i) * C_ + k0 + cc];
      }
      __syncthreads();
      const float* xr = &x_t[j][k0];
#pragma unroll
      for (int cs = 0; cs < KC; cs += 4) {
        float4 xv = *(const float4*)(xr + cs);
        float4 a4 = *(const float4*)(&cb_t[sg][cs]);
        float4 b4 = *(const float4*)(&cb_t[sg + 32][cs]);
        acc0 += xv.x * a4.x + xv.y * a4.y + xv.z * a4.z + xv.w * a4.w;
        acc1 += xv.x * b4.x + xv.y * b4.y + xv.z * b4.z + xv.w * b4.w;
      }
    }
    sc[s0 + sg][j] = (_Float16)acc0;
    sc[s0 + sg + 32][j] = (_Float16)acc1;
  }
  __syncthreads();

  // ---- top-KCAND extraction: 8 groups of 32 threads, group g owns p=g ----
  {
    const int g = tid >> 5, t = tid & 31;
    for (int pass = 0; pass < KCAND; ++pass) {
      float bv = -1e30f;
      int bs = 0;
      for (int k = 0; k < 64; ++k) {
        int s = t + 32 * k;
        float v = (float)sc[s][g];
        if (v > bv) { bv = v; bs = s; }
      }
#pragma unroll
      for (int off = 1; off < 32; off <<= 1) {  // offs<32: stays in 32-lane half
        float ov = __shfl_xor(bv, off);
        int os = __shfl_xor(bs, off);
        if (ov > bv || (ov == bv && os < bs)) { bv = ov; bs = os; }
      }
      if (t == 0) {
        cand_s[g][pass] = bs;
        sc[bs][g] = (_Float16)(-65504.f);
      }
      __syncthreads();
    }
  }

  // ---- np-fp32-exact rescore of candidates:
  //      xc = einsum semantics: acc=0; for c: acc = fl(acc + fl(x*cb))  (no FMA)
  //      c2 = order-insensitive (~0.002): fp64 sum of fp32-rounded squares
  //      d  = fl( fl(x2 + c2) - fl(2*xc) ) ----
  for (int task = tid; task < TPW * KCAND; task += 256) {
    int jj = task / KCAND, r = task % KCAND;
    int s = cand_s[jj][r];
    const float* row = cb + (size_t)s * C_;
    const float* xrow = &x_t[jj][0];
    float acc = 0.f;
    double c2d = 0.0;
    for (int c = 0; c < C_; c += 4) {
      float4 cv = *(const float4*)(row + c);
      acc = __fadd_rn(acc, __fmul_rn(xrow[c + 0], cv.x));
      acc = __fadd_rn(acc, __fmul_rn(xrow[c + 1], cv.y));
      acc = __fadd_rn(acc, __fmul_rn(xrow[c + 2], cv.z));
      acc = __fadd_rn(acc, __fmul_rn(xrow[c + 3], cv.w));
      c2d += (double)__fmul_rn(cv.x, cv.x);
      c2d += (double)__fmul_rn(cv.y, cv.y);
      c2d += (double)__fmul_rn(cv.z, cv.z);
      c2d += (double)__fmul_rn(cv.w, cv.w);
    }
    float c2f = (float)c2d;
    float d32 = __fsub_rn(__fadd_rn(x2f[jj], c2f), __fmul_rn(2.f, acc));
    dval[jj][r] = d32;
  }
  __syncthreads();

  // ---- ranks over fp32 d (ties -> smallest s = np.argmin first-index),
  //      weighted sum, argmin ----
  double contrib = 0.0;
  for (int task = tid; task < TPW * KCAND; task += 256) {
    int jj = task / KCAND, r = task % KCAND;
    float e = dval[jj][r];
    int s = cand_s[jj][r];
    int rank = 0;
    for (int r2 = 0; r2 < KCAND; ++r2) {
      float e2 = dval[jj][r2];
      int s2 = cand_s[jj][r2];
      rank += (e2 < e || (e2 == e && s2 < s)) ? 1 : 0;
    }
    contrib += exp((double)(-rank)) * (double)e;
    if (rank == 0) out[2 + n * P_ + p0 + jj] = (float)s;  // argmin index as float
  }
  __syncthreads();
#pragma unroll
  for (int off = 32; off > 0; off >>= 1) contrib += __shfl_down(contrib, off);
  if ((tid & 63) == 0) redd[tid >> 6] = contrib;
  __syncthreads();
  if (tid == 0) cb_partial[bx] = redd[0] + redd[1] + redd[2] + redd[3];
}

// ---------------- K2: straight-through output + commitment loss ----------------
__global__ __launch_bounds__(256) void k2_output(
    const float* __restrict__ x, const float* __restrict__ cb,
    float* __restrict__ out, double* __restrict__ commit_partial) {
  __shared__ double r2[4];
  const int tid = threadIdx.x;
  const int bx = blockIdx.x;
  const int n = bx >> 9, c = bx & 511;
  const int p = tid * 4;

  const float* xr = x + ((size_t)n * C_ + c) * P_ + p;
  float4 xv = *(const float4*)xr;
  float xs[4] = {xv.x, xv.y, xv.z, xv.w};
  const float* idxf = out + 2 + n * P_ + p;
  float o[4];
  float acc = 0.f;
#pragma unroll
  for (int k = 0; k < 4; ++k) {
    int s = (int)idxf[k];
    float q = cb[(size_t)s * C_ + c];
    float t = __fsub_rn(q, xs[k]);
    o[k] = __fadd_rn(xs[k], t);   // x + stop_grad(xq - x), ref rounding
    float dd = __fsub_rn(xs[k], q);
    acc += dd * dd;
  }
  float* orow = out + 2 + N_ * P_ + ((size_t)n * C_ + c) * P_ + p;
  ((float2*)orow)[0] = make_float2(o[0], o[1]);
  ((float2*)orow)[1] = make_float2(o[2], o[3]);

  double dacc = (double)acc;
#pragma unroll
  for (int off = 32; off > 0; off >>= 1) dacc += __shfl_down(dacc, off);
  if ((tid & 63) == 0) r2[tid >> 6] = dacc;
  __syncthreads();
  if (tid == 0) commit_partial[bx] = r2[0] + r2[1] + r2[2] + r2[3];
}

// ---------------- K3: finalize scalars ----------------
__global__ __launch_bounds__(256) void k3_finalize(
    const double* __restrict__ cb_partial, const double* __restrict__ commit_partial,
    float* __restrict__ out) {
  __shared__ double red[8];
  const int tid = threadIdx.x;
  double a = 0.0, b = 0.0;
  for (int i = tid; i < 4096; i += 256) a += cb_partial[i];
  for (int i = tid; i < 16384; i += 256) b += commit_partial[i];
#pragma unroll
  for (int off = 32; off > 0; off >>= 1) {
    a += __shfl_down(a, off);
    b += __shfl_down(b, off);
  }
  if ((tid & 63) == 0) {
    red[(tid >> 6) * 2 + 0] = a;
    red[(tid >> 6) * 2 + 1] = b;
  }
  __syncthreads();
  if (tid == 0) {
    double A = red[0] + red[2] + red[4] + red[6];
    double B = red[1] + red[3] + red[5] + red[7];
    out[0] = (float)(A / ((double)N_ * (double)S_ * (double)P_));
    out[1] = (float)(B / ((double)N_ * (double)C_ * (double)P_));
  }
}

extern "C" void kernel_launch(void* const* d_in, const int* in_sizes, int n_in,
                              void* d_out, int out_size, void* d_ws, size_t ws_size,
                              hipStream_t stream) {
  const float* x = (const float*)d_in[0];
  const float* cb = (const float*)d_in[1];
  float* out = (float*)d_out;
  double* cb_partial = (double*)d_ws;            // 4096 doubles
  double* commit_partial = cb_partial + 4096;    // 16384 doubles (ws: 160 KB)

  hipLaunchKernelGGL(k1_score_select, dim3(4096), dim3(256), 0, stream,
                     x, cb, out, cb_partial);
  hipLaunchKernelGGL(k2_output, dim3(16384), dim3(256), 0, stream,
                     x, cb, out, commit_partial);
  hipLaunchKernelGGL(k3_finalize, dim3(1), dim3(256), 0, stream,
                     cb_partial, commit_partial, out);
}

// Round 3
// 741.281 us; speedup vs baseline: 5.9326x; 5.9326x over previous
//
#include <hip/hip_runtime.h>
#include <hip/hip_fp16.h>

#define N_ 32
#define C_ 512
#define P_ 1024
#define S_ 2048
#define KCAND 24   // argmin needs winner in top-24 by bf16 score: ~290 sigma margin

typedef __attribute__((ext_vector_type(8))) short sh8;
typedef __attribute__((ext_vector_type(4))) float fx4;

// ---- ws layout (bytes) ----
#define WS_SCORES   0ull                       // _Float16 [32768][2048] = 134217728
#define WS_XT       134217728ull               // ushort bf16 [32768][512] = 33554432
#define WS_CBT      167772160ull               // ushort bf16 [2048][512]  = 2097152
#define WS_C2F      169869312ull               // float [2048]             = 8192
#define WS_X2       169877504ull               // float [32768]            = 131072
#define WS_ROWPART  170008576ull               // double [32768]           = 262144
#define WS_COMMIT   170270720ull               // double [16384]           = 131072
#define WS_TOTAL    170401792ull

__device__ __forceinline__ unsigned short f2bf(float f) {
  union { float f; unsigned u; } x; x.f = f;
  unsigned r = x.u + 0x7fffu + ((x.u >> 16) & 1u);
  return (unsigned short)(r >> 16);
}

template <typename T>
__device__ __forceinline__ void load16_lds(const T* g, T* l) {
  __builtin_amdgcn_global_load_lds((const __attribute__((address_space(1))) void*)g,
                                   (__attribute__((address_space(3))) void*)l, 16, 0, 0);
}

// ---------------- cvt codebook to bf16 + c2 (fp64 sum of fp32 squares -> fp32) ----
__global__ __launch_bounds__(64) void k_cvt_cb(const float* __restrict__ cb,
                                               unsigned short* __restrict__ cbT,
                                               float* __restrict__ c2f) {
  const int s = blockIdx.x, l = threadIdx.x;
  const float* row = cb + (size_t)s * C_;
  double c2d = 0.0;
#pragma unroll
  for (int h = 0; h < 2; ++h) {
    int c = h * 256 + l * 4;
    float4 v = *(const float4*)(row + c);
    ushort4 o;
    o.x = f2bf(v.x); o.y = f2bf(v.y); o.z = f2bf(v.z); o.w = f2bf(v.w);
    *(ushort4*)(cbT + (size_t)s * C_ + c) = o;
    c2d += (double)__fmul_rn(v.x, v.x) + (double)__fmul_rn(v.y, v.y) +
           (double)__fmul_rn(v.z, v.z) + (double)__fmul_rn(v.w, v.w);
  }
#pragma unroll
  for (int off = 32; off > 0; off >>= 1) c2d += __shfl_down(c2d, off);
  if (l == 0) c2f[s] = (float)c2d;
}

// ---------------- x2 per row: numpy sequential fp32 chain over c ----------------
__global__ __launch_bounds__(256) void k_x2(const float* __restrict__ x,
                                            float* __restrict__ x2ws) {
  const int n = blockIdx.x >> 2;
  const int p = ((blockIdx.x & 3) << 8) + threadIdx.x;
  const float* xp = x + (size_t)n * (C_ * P_) + p;
  float acc = 0.f;
  for (int c = 0; c < C_; ++c) {
    float t = xp[(size_t)c * P_];
    acc = __fadd_rn(acc, __fmul_rn(t, t));
  }
  x2ws[n * P_ + p] = acc;
}

// ---------------- transpose+cvt x: [n][c][p] fp32 -> xT[n*P+p][c] bf16 ----------
__global__ __launch_bounds__(256) void k_transpose_x(const float* __restrict__ x,
                                                     unsigned short* __restrict__ xT) {
  __shared__ float tile[64][65];
  const int tid = threadIdx.x, bx = blockIdx.x;
  const int n = bx >> 7, pt = (bx & 127) >> 3, ct = bx & 7;
  const int p0 = pt * 64, c0 = ct * 64;
#pragma unroll
  for (int pp = 0; pp < 4; ++pp) {
    int cl = (tid >> 4) + pp * 16;
    int pl4 = (tid & 15) * 4;
    float4 v = *(const float4*)(x + (size_t)n * (C_ * P_) + (size_t)(c0 + cl) * P_ + p0 + pl4);
    tile[cl][pl4 + 0] = v.x; tile[cl][pl4 + 1] = v.y;
    tile[cl][pl4 + 2] = v.z; tile[cl][pl4 + 3] = v.w;
  }
  __syncthreads();
#pragma unroll
  for (int pp = 0; pp < 4; ++pp) {
    int pl = (tid >> 4) + pp * 16;
    int cl4 = (tid & 15) * 4;
    ushort4 o;
    o.x = f2bf(tile[cl4 + 0][pl]); o.y = f2bf(tile[cl4 + 1][pl]);
    o.z = f2bf(tile[cl4 + 2][pl]); o.w = f2bf(tile[cl4 + 3][pl]);
    *(ushort4*)(xT + (size_t)(n * P_ + p0 + pl) * C_ + c0 + cl4) = o;
  }
}

// ---------------- MFMA GEMM: scores[m][s] = sum_c xT[m][c]*cbT[s][c], fp16 out ----
// 128x128 tile, BK=64, 4 waves (2x2 of 64x64), XOR-swizzled LDS, global_load_lds 16B.
__global__ __launch_bounds__(256, 4) void k_gemm(const unsigned short* __restrict__ xT,
                                                 const unsigned short* __restrict__ cbT,
                                                 _Float16* __restrict__ scores) {
  __shared__ unsigned short As[128 * 64];  // 16 KB, chunk (m*8 + (k8 ^ (m&7)))
  __shared__ unsigned short Bs[128 * 64];
  const int tid = threadIdx.x;
  const int w = tid >> 6, l = tid & 63;
  const int bx = blockIdx.x;
  const int m0 = (bx >> 4) << 7, s0 = (bx & 15) << 7;
  const int wm = (w & 1) << 6, wsf = (w >> 1) << 6;
  const int quad = l >> 4, lane15 = l & 15;

  // staging addresses (kk-invariant parts)
  size_t gA[4], gB[4];
  unsigned short *lA[4], *lB[4];
#pragma unroll
  for (int q = 0; q < 4; ++q) {
    int chunk = (q * 4 + w) * 64 + l;
    int m = chunk >> 3, k8s = chunk & 7;
    int k8 = k8s ^ (m & 7);
    gA[q] = (size_t)(m0 + m) * (C_ * 2) + (size_t)k8 * 16;
    gB[q] = (size_t)(s0 + m) * (C_ * 2) + (size_t)k8 * 16;
    lA[q] = As + (q * 4 + w) * 512;  // wave-uniform base; HW appends lane*16
    lB[q] = Bs + (q * 4 + w) * 512;
  }
  const char* xb = (const char*)xT;
  const char* cbb = (const char*)cbT;

  fx4 acc[4][4];
#pragma unroll
  for (int i = 0; i < 4; ++i)
#pragma unroll
    for (int j = 0; j < 4; ++j) acc[i][j] = (fx4){0.f, 0.f, 0.f, 0.f};

  for (int kk = 0; kk < 8; ++kk) {
#pragma unroll
    for (int q = 0; q < 4; ++q) {
      load16_lds((const unsigned short*)(xb + gA[q] + (size_t)kk * 128), lA[q]);
      load16_lds((const unsigned short*)(cbb + gB[q] + (size_t)kk * 128), lB[q]);
    }
    __syncthreads();
#pragma unroll
    for (int ks = 0; ks < 2; ++ks) {
      const int k8g = ks * 4 + quad;
      sh8 af[4], bf[4];
#pragma unroll
      for (int mi = 0; mi < 4; ++mi) {
        int m = wm + mi * 16 + lane15;
        af[mi] = *(const sh8*)(As + m * 64 + (k8g ^ (m & 7)) * 8);
      }
#pragma unroll
      for (int si = 0; si < 4; ++si) {
        int s = wsf + si * 16 + lane15;
        bf[si] = *(const sh8*)(Bs + s * 64 + (k8g ^ (s & 7)) * 8);
      }
#pragma unroll
      for (int mi = 0; mi < 4; ++mi)
#pragma unroll
        for (int si = 0; si < 4; ++si)
          acc[mi][si] = __builtin_amdgcn_mfma_f32_16x16x32_bf16(af[mi], bf[si], acc[mi][si], 0, 0, 0);
    }
    __syncthreads();
  }

  // C/D: col = lane&15 (s), row = quad*4 + reg (m)
#pragma unroll
  for (int mi = 0; mi < 4; ++mi) {
    int rowb = m0 + wm + mi * 16 + quad * 4;
#pragma unroll
    for (int si = 0; si < 4; ++si) {
      int col = s0 + wsf + si * 16 + lane15;
      _Float16* dst = scores + (size_t)rowb * S_ + col;
#pragma unroll
      for (int r = 0; r < 4; ++r) dst[(size_t)r * S_] = (_Float16)acc[mi][si][r];
    }
  }
}

// ---------------- phase 2: top-K select + np-fp32 rescore + ranks/argmin/loss ----
__global__ __launch_bounds__(256, 4) void k_phase2(
    const float* __restrict__ x, const float* __restrict__ cb,
    const _Float16* __restrict__ scores, const float* __restrict__ c2f,
    const float* __restrict__ x2ws, float* __restrict__ out,
    double* __restrict__ rowpart) {
  __shared__ float xrow[4][C_];
  const int tid = threadIdx.x;
  const int w = tid >> 6, l = tid & 63;
  const int R = blockIdx.x * 4 + w;
  const int n = R >> 10, p = R & 1023;

  // stage x row (fp32 exact) into LDS early
#pragma unroll
  for (int k = 0; k < 8; ++k)
    xrow[w][k * 64 + l] = x[(size_t)n * (C_ * P_) + (size_t)(k * 64 + l) * P_ + p];

  // load this row's 2048 fp16 scores: lane l owns s = l*32 + j
  float v[32];
  {
    const uint4* s4 = (const uint4*)(scores + (size_t)R * S_ + (size_t)l * 32);
    union { uint4 u; _Float16 h[8]; } t;
#pragma unroll
    for (int i = 0; i < 4; ++i) {
      t.u = s4[i];
#pragma unroll
      for (int j = 0; j < 8; ++j) v[i * 8 + j] = (float)t.h[j];
    }
  }

  // top-KCAND by score (max xc == min distance); ties -> smaller s
  int mys = 0;
  unsigned removed = 0;
  for (int pass = 0; pass < KCAND; ++pass) {
    float bv = -1e30f; int bj = 0;
#pragma unroll
    for (int j = 0; j < 32; ++j) {
      bool ok = (((removed >> j) & 1u) == 0u) && (v[j] > bv);
      bv = ok ? v[j] : bv;
      bj = ok ? j : bj;
    }
    float cv = bv; int cs = l * 32 + bj;
#pragma unroll
    for (int off = 1; off < 64; off <<= 1) {
      float ov = __shfl_xor(cv, off);
      int os = __shfl_xor(cs, off);
      if (ov > cv || (ov == cv && os < cs)) { cv = ov; cs = os; }
    }
    if (l == pass) mys = cs;
    if ((cs >> 5) == l) removed |= (1u << (cs & 31));
  }
  __syncthreads();

  // np-fp32-exact rescore: acc=0; for c: acc = fl(acc + fl(x*cb)); no FMA
  float d32 = 0.f;
  if (l < KCAND) {
    const float4* crow = (const float4*)(cb + (size_t)mys * C_);
    float acc = 0.f;
    for (int i = 0; i < C_ / 4; ++i) {
      float4 cv = crow[i];
      float4 xv = *(const float4*)&xrow[w][i * 4];  // broadcast
      acc = __fadd_rn(acc, __fmul_rn(xv.x, cv.x));
      acc = __fadd_rn(acc, __fmul_rn(xv.y, cv.y));
      acc = __fadd_rn(acc, __fmul_rn(xv.z, cv.z));
      acc = __fadd_rn(acc, __fmul_rn(xv.w, cv.w));
    }
    d32 = __fsub_rn(__fadd_rn(x2ws[R], c2f[mys]), __fmul_rn(2.f, acc));
  }

  // exact ranks among candidates (fp32 values, ties -> smaller s)
  int rank = 0;
#pragma unroll
  for (int k = 0; k < KCAND; ++k) {
    float dk = __shfl(d32, k);
    int sk = __shfl(mys, k);
    rank += (dk < d32 || (dk == d32 && sk < mys)) ? 1 : 0;
  }
  if (l < KCAND && rank == 0) out[2 + R] = (float)mys;

  double contrib = (l < KCAND) ? exp(-(double)rank) * (double)d32 : 0.0;
#pragma unroll
  for (int off = 32; off > 0; off >>= 1) contrib += __shfl_down(contrib, off);
  if (l == 0) rowpart[R] = contrib;
}

// ---------------- K2: straight-through output + commitment loss ----------------
__global__ __launch_bounds__(256) void k2_output(
    const float* __restrict__ x, const float* __restrict__ cb,
    float* __restrict__ out, double* __restrict__ commit_partial) {
  __shared__ double r2[4];
  const int tid = threadIdx.x;
  const int bx = blockIdx.x;
  const int n = bx >> 9, c = bx & 511;
  const int p = tid * 4;

  const float* xr = x + ((size_t)n * C_ + c) * P_ + p;
  float4 xv = *(const float4*)xr;
  float xs[4] = {xv.x, xv.y, xv.z, xv.w};
  const float* idxf = out + 2 + n * P_ + p;
  float o[4];
  float acc = 0.f;
#pragma unroll
  for (int k = 0; k < 4; ++k) {
    int s = (int)idxf[k];
    float q = cb[(size_t)s * C_ + c];
    float t = __fsub_rn(q, xs[k]);
    o[k] = __fadd_rn(xs[k], t);
    float dd = __fsub_rn(xs[k], q);
    acc += dd * dd;
  }
  float* orow = out + 2 + N_ * P_ + ((size_t)n * C_ + c) * P_ + p;
  ((float2*)orow)[0] = make_float2(o[0], o[1]);
  ((float2*)orow)[1] = make_float2(o[2], o[3]);

  double dacc = (double)acc;
#pragma unroll
  for (int off = 32; off > 0; off >>= 1) dacc += __shfl_down(dacc, off);
  if ((tid & 63) == 0) r2[tid >> 6] = dacc;
  __syncthreads();
  if (tid == 0) commit_partial[bx] = r2[0] + r2[1] + r2[2] + r2[3];
}

// ---------------- K3: finalize scalars (parameterized partial counts) ----------
__global__ __launch_bounds__(256) void k3_finalize(
    const double* __restrict__ pa, int na, const double* __restrict__ pb, int nb,
    float* __restrict__ out) {
  __shared__ double red[8];
  const int tid = threadIdx.x;
  double a = 0.0, b = 0.0;
  for (int i = tid; i < na; i += 256) a += pa[i];
  for (int i = tid; i < nb; i += 256) b += pb[i];
#pragma unroll
  for (int off = 32; off > 0; off >>= 1) {
    a += __shfl_down(a, off);
    b += __shfl_down(b, off);
  }
  if ((tid & 63) == 0) {
    red[(tid >> 6) * 2 + 0] = a;
    red[(tid >> 6) * 2 + 1] = b;
  }
  __syncthreads();
  if (tid == 0) {
    double A = red[0] + red[2] + red[4] + red[6];
    double B = red[1] + red[3] + red[5] + red[7];
    out[0] = (float)(A / ((double)N_ * (double)S_ * (double)P_));
    out[1] = (float)(B / ((double)N_ * (double)C_ * (double)P_));
  }
}

// ======================= round-2 fallback (small-ws path) =======================
#define TPW 8
#define KC 32
#define SC 64
#define KCF 48
__global__ __launch_bounds__(256) void k1_fallback(
    const float* __restrict__ x, const float* __restrict__ cb,
    float* __restrict__ out, double* __restrict__ cb_partial) {
  __shared__ float dval[TPW][KCF];
  __shared__ float x2f[TPW];
  __shared__ double redd[4];
  __shared__ float x_t[TPW][C_ + 4];
  __shared__ float cb_t[SC][KC + 4];
  __shared__ int cand_s[TPW][KCF];
  __shared__ _Float16 sc[S_][TPW];

  const int tid = threadIdx.x;
  const int bx = blockIdx.x;
  const int n = bx >> 7;
  const int p0 = (bx & 127) * TPW;

  const float* xn = x + (size_t)n * C_ * P_ + p0;
#pragma unroll
  for (int q = 0; q < 16; ++q) {
    int e = tid + 256 * q;
    int c = e >> 3, j = e & 7;
    x_t[j][c] = xn[(size_t)c * P_ + j];
  }
  __syncthreads();
  if (tid < TPW) {
    float acc = 0.f;
    for (int c = 0; c < C_; ++c)
      acc = __fadd_rn(acc, __fmul_rn(x_t[tid][c], x_t[tid][c]));
    x2f[tid] = acc;
  }
  const int j = tid & 7;
  const int sg = tid >> 3;
  for (int s0 = 0; s0 < S_; s0 += SC) {
    float acc0 = 0.f, acc1 = 0.f;
    for (int k0 = 0; k0 < C_; k0 += KC) {
      __syncthreads();
#pragma unroll
      for (int q = 0; q < 8; ++q) {
        int e = tid + 256 * q;
        int i = e >> 5, cc = e & 31;
        cb_t[i][cc] = cb[(size_t)(s0 + i) * C_ + k0 + cc];
      }
      __syncthreads();
      const float* xr = &x_t[j][k0];
#pragma unroll
      for (int cs = 0; cs < KC; cs += 4) {
        float4 xv = *(const float4*)(xr + cs);
        float4 a4 = *(const float4*)(&cb_t[sg][cs]);
        float4 b4 = *(const float4*)(&cb_t[sg + 32][cs]);
        acc0 += xv.x * a4.x + xv.y * a4.y + xv.z * a4.z + xv.w * a4.w;
        acc1 += xv.x * b4.x + xv.y * b4.y + xv.z * b4.z + xv.w * b4.w;
      }
    }
    sc[s0 + sg][j] = (_Float16)acc0;
    sc[s0 + sg + 32][j] = (_Float16)acc1;
  }
  __syncthreads();
  {
    const int g = tid >> 5, t = tid & 31;
    for (int pass = 0; pass < KCF; ++pass) {
      float bv = -1e30f;
      int bs = 0;
      for (int k = 0; k < 64; ++k) {
        int s = t + 32 * k;
        float vv = (float)sc[s][g];
        if (vv > bv) { bv = vv; bs = s; }
      }
#pragma unroll
      for (int off = 1; off < 32; off <<= 1) {
        float ov = __shfl_xor(bv, off);
        int os = __shfl_xor(bs, off);
        if (ov > bv || (ov == bv && os < bs)) { bv = ov; bs = os; }
      }
      if (t == 0) {
        cand_s[g][pass] = bs;
        sc[bs][g] = (_Float16)(-65504.f);
      }
      __syncthreads();
    }
  }
  for (int task = tid; task < TPW * KCF; task += 256) {
    int jj = task / KCF, r = task % KCF;
    int s = cand_s[jj][r];
    const float* row = cb + (size_t)s * C_;
    const float* xrw = &x_t[jj][0];
    float acc = 0.f;
    double c2d = 0.0;
    for (int c = 0; c < C_; c += 4) {
      float4 cv = *(const float4*)(row + c);
      acc = __fadd_rn(acc, __fmul_rn(xrw[c + 0], cv.x));
      acc = __fadd_rn(acc, __fmul_rn(xrw[c + 1], cv.y));
      acc = __fadd_rn(acc, __fmul_rn(xrw[c + 2], cv.z));
      acc = __fadd_rn(acc, __fmul_rn(xrw[c + 3], cv.w));
      c2d += (double)__fmul_rn(cv.x, cv.x);
      c2d += (double)__fmul_rn(cv.y, cv.y);
      c2d += (double)__fmul_rn(cv.z, cv.z);
      c2d += (double)__fmul_rn(cv.w, cv.w);
    }
    float c2s = (float)c2d;
    dval[jj][r] = __fsub_rn(__fadd_rn(x2f[jj], c2s), __fmul_rn(2.f, acc));
  }
  __syncthreads();
  double contrib = 0.0;
  for (int task = tid; task < TPW * KCF; task += 256) {
    int jj = task / KCF, r = task % KCF;
    float e = dval[jj][r];
    int s = cand_s[jj][r];
    int rank = 0;
    for (int r2 = 0; r2 < KCF; ++r2) {
      float e2 = dval[jj][r2];
      int s2 = cand_s[jj][r2];
      rank += (e2 < e || (e2 == e && s2 < s)) ? 1 : 0;
    }
    contrib += exp((double)(-rank)) * (double)e;
    if (rank == 0) out[2 + n * P_ + p0 + jj] = (float)s;
  }
  __syncthreads();
#pragma unroll
  for (int off = 32; off > 0; off >>= 1) contrib += __shfl_down(contrib, off);
  if ((tid & 63) == 0) redd[tid >> 6] = contrib;
  __syncthreads();
  if (tid == 0) cb_partial[bx] = redd[0] + redd[1] + redd[2] + redd[3];
}

extern "C" void kernel_launch(void* const* d_in, const int* in_sizes, int n_in,
                              void* d_out, int out_size, void* d_ws, size_t ws_size,
                              hipStream_t stream) {
  const float* x = (const float*)d_in[0];
  const float* cb = (const float*)d_in[1];
  float* out = (float*)d_out;
  char* ws = (char*)d_ws;

  if (ws_size >= WS_TOTAL) {
    _Float16* scores = (_Float16*)(ws + WS_SCORES);
    unsigned short* xT = (unsigned short*)(ws + WS_XT);
    unsigned short* cbT = (unsigned short*)(ws + WS_CBT);
    float* c2f = (float*)(ws + WS_C2F);
    float* x2ws = (float*)(ws + WS_X2);
    double* rowpart = (double*)(ws + WS_ROWPART);
    double* commitp = (double*)(ws + WS_COMMIT);

    hipLaunchKernelGGL(k_cvt_cb, dim3(S_), dim3(64), 0, stream, cb, cbT, c2f);
    hipLaunchKernelGGL(k_x2, dim3(128), dim3(256), 0, stream, x, x2ws);
    hipLaunchKernelGGL(k_transpose_x, dim3(4096), dim3(256), 0, stream, x, xT);
    hipLaunchKernelGGL(k_gemm, dim3(4096), dim3(256), 0, stream, xT, cbT, scores);
    hipLaunchKernelGGL(k_phase2, dim3(8192), dim3(256), 0, stream,
                       x, cb, scores, c2f, x2ws, out, rowpart);
    hipLaunchKernelGGL(k2_output, dim3(16384), dim3(256), 0, stream, x, cb, out, commitp);
    hipLaunchKernelGGL(k3_finalize, dim3(1), dim3(256), 0, stream,
                       rowpart, N_ * P_, commitp, 16384, out);
  } else {
    double* cb_partial = (double*)d_ws;
    double* commitp = cb_partial + 4096;
    hipLaunchKernelGGL(k1_fallback, dim3(4096), dim3(256), 0, stream, x, cb, out, cb_partial);
    hipLaunchKernelGGL(k2_output, dim3(16384), dim3(256), 0, stream, x, cb, out, commitp);
    hipLaunchKernelGGL(k3_finalize, dim3(1), dim3(256), 0, stream,
                       cb_partial, 4096, commitp, 16384, out);
  }
}

// Round 4
// 540.158 us; speedup vs baseline: 8.1416x; 1.3723x over previous
//
#include <hip/hip_runtime.h>
#include <hip/hip_fp16.h>

#define N_ 32
#define C_ 512
#define P_ 1024
#define S_ 2048
#define NR_ (N_ * P_)   // 32768 rows
#define GUARD 6e-3f     // ~24 sigma of bf16-score noise; np-rescore set radius
#define TSIG 2.3f       // candidate threshold in row-sigma units

typedef __attribute__((ext_vector_type(8))) short sh8;
typedef __attribute__((ext_vector_type(4))) float fx4;

// ---- ws layout (bytes) ----
#define WS_XT       0ull            // ushort bf16 [32768][512] = 33554432
#define WS_XTF      33554432ull     // float [32768][512]       = 67108864
#define WS_CBT      100663296ull    // ushort bf16 [2048][512]  = 2097152
#define WS_C2F      102760448ull    // float [2048]             = 8192
#define WS_X2       102768640ull    // float [32768]            = 131072
#define WS_CNT      102899712ull    // int [32768]              = 131072
#define WS_CANDV    103030784ull    // float [32768][64]        = 8388608
#define WS_CANDS    111419392ull    // int [32768][64]          = 8388608
#define WS_ROWPART  119808000ull    // double [32768]           = 262144
#define WS_COMMIT   120070144ull    // double [16384]           = 131072
#define WS_TOTAL    120201216ull

__device__ __forceinline__ unsigned short f2bf(float f) {
  union { float f; unsigned u; } x; x.f = f;
  unsigned r = x.u + 0x7fffu + ((x.u >> 16) & 1u);
  return (unsigned short)(r >> 16);
}

template <typename T>
__device__ __forceinline__ void load16_lds(const T* g, T* l) {
  __builtin_amdgcn_global_load_lds((const __attribute__((address_space(1))) void*)g,
                                   (__attribute__((address_space(3))) void*)l, 16, 0, 0);
}

// ---------------- cvt codebook to bf16 + c2 (fp64 sum of fp32 squares -> fp32) ----
__global__ __launch_bounds__(64) void k_cvt_cb(const float* __restrict__ cb,
                                               unsigned short* __restrict__ cbT,
                                               float* __restrict__ c2f) {
  const int s = blockIdx.x, l = threadIdx.x;
  const float* row = cb + (size_t)s * C_;
  double c2d = 0.0;
#pragma unroll
  for (int h = 0; h < 2; ++h) {
    int c = h * 256 + l * 4;
    float4 v = *(const float4*)(row + c);
    ushort4 o;
    o.x = f2bf(v.x); o.y = f2bf(v.y); o.z = f2bf(v.z); o.w = f2bf(v.w);
    *(ushort4*)(cbT + (size_t)s * C_ + c) = o;
    c2d += (double)__fmul_rn(v.x, v.x) + (double)__fmul_rn(v.y, v.y) +
           (double)__fmul_rn(v.z, v.z) + (double)__fmul_rn(v.w, v.w);
  }
#pragma unroll
  for (int off = 32; off > 0; off >>= 1) c2d += __shfl_down(c2d, off);
  if (l == 0) c2f[s] = (float)c2d;
}

// ---------------- x2 per row (np sequential fp32 chain) + zero cnt ----------------
__global__ __launch_bounds__(256) void k_x2(const float* __restrict__ x,
                                            float* __restrict__ x2ws,
                                            int* __restrict__ cnt) {
  const int n = blockIdx.x >> 2;
  const int p = ((blockIdx.x & 3) << 8) + threadIdx.x;
  const float* xp = x + (size_t)n * (C_ * P_) + p;
  float acc = 0.f;
  for (int c = 0; c < C_; ++c) {
    float t = xp[(size_t)c * P_];
    acc = __fadd_rn(acc, __fmul_rn(t, t));
  }
  x2ws[n * P_ + p] = acc;
  cnt[n * P_ + p] = 0;
}

// ---------------- transpose x: [n][c][p] fp32 -> xT bf16 [R][c] + xTf fp32 [R][c] --
__global__ __launch_bounds__(256) void k_transpose_x(const float* __restrict__ x,
                                                     unsigned short* __restrict__ xT,
                                                     float* __restrict__ xTf) {
  __shared__ float tile[64][65];
  const int tid = threadIdx.x, bx = blockIdx.x;
  const int n = bx >> 7, pt = (bx & 127) >> 3, ct = bx & 7;
  const int p0 = pt * 64, c0 = ct * 64;
#pragma unroll
  for (int pp = 0; pp < 4; ++pp) {
    int cl = (tid >> 4) + pp * 16;
    int pl4 = (tid & 15) * 4;
    float4 v = *(const float4*)(x + (size_t)n * (C_ * P_) + (size_t)(c0 + cl) * P_ + p0 + pl4);
    tile[cl][pl4 + 0] = v.x; tile[cl][pl4 + 1] = v.y;
    tile[cl][pl4 + 2] = v.z; tile[cl][pl4 + 3] = v.w;
  }
  __syncthreads();
#pragma unroll
  for (int pp = 0; pp < 4; ++pp) {
    int pl = (tid >> 4) + pp * 16;
    int cl4 = (tid & 15) * 4;
    float4 f;
    f.x = tile[cl4 + 0][pl]; f.y = tile[cl4 + 1][pl];
    f.z = tile[cl4 + 2][pl]; f.w = tile[cl4 + 3][pl];
    ushort4 o;
    o.x = f2bf(f.x); o.y = f2bf(f.y); o.z = f2bf(f.z); o.w = f2bf(f.w);
    size_t R = (size_t)(n * P_ + p0 + pl);
    *(ushort4*)(xT + R * C_ + c0 + cl4) = o;
    *(float4*)(xTf + R * C_ + c0 + cl4) = f;
  }
}

// ---------------- MFMA GEMM + threshold epilogue -> per-row candidate lists -------
// 128x128 tile, BK=64, 4 waves (2x2 of 64x64), XOR-swizzled LDS, global_load_lds 16B.
__global__ __launch_bounds__(256, 4) void k_gemm(const unsigned short* __restrict__ xT,
                                                 const unsigned short* __restrict__ cbT,
                                                 const float* __restrict__ x2ws,
                                                 float* __restrict__ candv,
                                                 int* __restrict__ cands,
                                                 int* __restrict__ cnt) {
  __shared__ unsigned short As[128 * 64];  // 16 KB, chunk (m*8 + (k8 ^ (m&7)))
  __shared__ unsigned short Bs[128 * 64];
  __shared__ float t_lds[128];
  const int tid = threadIdx.x;
  const int w = tid >> 6, l = tid & 63;
  const int bx = blockIdx.x;
  const int m0 = (bx >> 4) << 7, s0 = (bx & 15) << 7;
  const int wm = (w & 1) << 6, wsf = (w >> 1) << 6;
  const int quad = l >> 4, lane15 = l & 15;

  if (tid < 128) t_lds[tid] = TSIG * __fsqrt_rn(x2ws[m0 + tid]) * (1.0f / 512.0f);

  size_t gA[4], gB[4];
  unsigned short *lA[4], *lB[4];
#pragma unroll
  for (int q = 0; q < 4; ++q) {
    int chunk = (q * 4 + w) * 64 + l;
    int m = chunk >> 3, k8s = chunk & 7;
    int k8 = k8s ^ (m & 7);
    gA[q] = (size_t)(m0 + m) * (C_ * 2) + (size_t)k8 * 16;
    gB[q] = (size_t)(s0 + m) * (C_ * 2) + (size_t)k8 * 16;
    lA[q] = As + (q * 4 + w) * 512;
    lB[q] = Bs + (q * 4 + w) * 512;
  }
  const char* xb = (const char*)xT;
  const char* cbb = (const char*)cbT;

  fx4 acc[4][4];
#pragma unroll
  for (int i = 0; i < 4; ++i)
#pragma unroll
    for (int j = 0; j < 4; ++j) acc[i][j] = (fx4){0.f, 0.f, 0.f, 0.f};

  for (int kk = 0; kk < 8; ++kk) {
#pragma unroll
    for (int q = 0; q < 4; ++q) {
      load16_lds((const unsigned short*)(xb + gA[q] + (size_t)kk * 128), lA[q]);
      load16_lds((const unsigned short*)(cbb + gB[q] + (size_t)kk * 128), lB[q]);
    }
    __syncthreads();
#pragma unroll
    for (int ks = 0; ks < 2; ++ks) {
      const int k8g = ks * 4 + quad;
      sh8 af[4], bf[4];
#pragma unroll
      for (int mi = 0; mi < 4; ++mi) {
        int m = wm + mi * 16 + lane15;
        af[mi] = *(const sh8*)(As + m * 64 + (k8g ^ (m & 7)) * 8);
      }
#pragma unroll
      for (int si = 0; si < 4; ++si) {
        int s = wsf + si * 16 + lane15;
        bf[si] = *(const sh8*)(Bs + s * 64 + (k8g ^ (s & 7)) * 8);
      }
#pragma unroll
      for (int mi = 0; mi < 4; ++mi)
#pragma unroll
        for (int si = 0; si < 4; ++si)
          acc[mi][si] = __builtin_amdgcn_mfma_f32_16x16x32_bf16(af[mi], bf[si], acc[mi][si], 0, 0, 0);
    }
    __syncthreads();
  }

  // Epilogue: threshold appends + per-slab row-max guarantee.
  // C/D layout (verified r3): row = wm+mi*16+quad*4+r, col = s0+wsf+si*16+lane15.
#pragma unroll
  for (int mi = 0; mi < 4; ++mi) {
#pragma unroll
    for (int r = 0; r < 4; ++r) {
      const int rowl = wm + mi * 16 + quad * 4 + r;
      const int rowg = m0 + rowl;
      const float t = t_lds[rowl];
      float vmax = -1e30f; int smax = 0;
#pragma unroll
      for (int si = 0; si < 4; ++si) {
        float v = acc[mi][si][r];
        int s = s0 + wsf + si * 16 + lane15;
        if (v > vmax) { vmax = v; smax = s; }
        if (v >= t) {
          int slot = atomicAdd(&cnt[rowg], 1);
          if (slot < 64) { candv[(size_t)rowg * 64 + slot] = v; cands[(size_t)rowg * 64 + slot] = s; }
        }
      }
#pragma unroll
      for (int off = 1; off < 16; off <<= 1) {
        float ov = __shfl_xor(vmax, off);
        int os = __shfl_xor(smax, off);
        if (ov > vmax) { vmax = ov; smax = os; }
      }
      if (lane15 == 0 && vmax < t) {
        int slot = atomicAdd(&cnt[rowg], 1);
        if (slot < 64) { candv[(size_t)rowg * 64 + slot] = vmax; cands[(size_t)rowg * 64 + slot] = smax; }
      }
    }
  }
}

// ---------------- phase 2: ranks/loss from d~, lazy np-fp32 rescore for argmin ----
__global__ __launch_bounds__(256, 4) void k_phase2(
    const float* __restrict__ cb, const float* __restrict__ xTf,
    const float* __restrict__ candvG, const int* __restrict__ candsG,
    const int* __restrict__ cntG, const float* __restrict__ c2f,
    const float* __restrict__ x2ws, float* __restrict__ out,
    double* __restrict__ rowpart) {
  __shared__ float xrow[4][C_];
  const int tid = threadIdx.x;
  const int w = tid >> 6, l = tid & 63;
  const int R = blockIdx.x * 4 + w;

  const int cnt = min(cntG[R], 64);
  const float x2f = x2ws[R];
  const bool act = l < cnt;
  float v = candvG[(size_t)R * 64 + l];           // in-bounds always; poison if !act
  int s = candsG[(size_t)R * 64 + l];
  v = act ? v : -1e30f;
  s = act ? s : 0x7fffffff;
  const int sIdx = act ? s : 0;
  const float dt = act
      ? __fsub_rn(__fadd_rn(x2f, c2f[sIdx]), __fmul_rn(2.f, v))
      : 1e30f;

  // wave max score
  float M = v;
#pragma unroll
  for (int off = 1; off < 64; off <<= 1) M = fmaxf(M, __shfl_xor(M, off));

  // global ranks by d~ (ties -> smaller s)
  int rank = 0;
  for (int k = 0; k < 64; ++k) {
    float dk = __shfl(dt, k);
    int sk = __shfl(s, k);
    rank += (dk < dt || (dk == dt && sk < s)) ? 1 : 0;
  }

  // loss partial
  double contrib = act ? (double)__expf(-(float)rank) * (double)dt : 0.0;
#pragma unroll
  for (int off = 32; off > 0; off >>= 1) contrib += __shfl_down(contrib, off);
  if (l == 0) rowpart[R] = contrib;

  // argmin: np-exact only among near-top scores
  const bool near = act && (v >= M - GUARD);
  const unsigned long long bal = __ballot(near);
  const int nres = __popcll(bal);
  if (nres == 1) {
    int src = __ffsll(bal) - 1;
    int wins = __shfl(s, src);
    if (l == 0) out[2 + R] = (float)wins;
  } else {
    // stage exact x row (contiguous from xTf)
#pragma unroll
    for (int k = 0; k < 2; ++k)
      *(float4*)&xrow[w][l * 8 + k * 4] = *(const float4*)(xTf + (size_t)R * C_ + l * 8 + k * 4);
    float d32 = 1e30f;
    if (near) {
      const float4* crow = (const float4*)(cb + (size_t)s * C_);
      float acc = 0.f;
#pragma unroll 8
      for (int i = 0; i < C_ / 4; ++i) {
        float4 cv = crow[i];
        float4 xv = *(const float4*)&xrow[w][i * 4];
        acc = __fadd_rn(acc, __fmul_rn(xv.x, cv.x));
        acc = __fadd_rn(acc, __fmul_rn(xv.y, cv.y));
        acc = __fadd_rn(acc, __fmul_rn(xv.z, cv.z));
        acc = __fadd_rn(acc, __fmul_rn(xv.w, cv.w));
      }
      d32 = __fsub_rn(__fadd_rn(x2f, c2f[s]), __fmul_rn(2.f, acc));
    }
    float bd = d32;
    int bs2 = near ? s : 0x7fffffff;
#pragma unroll
    for (int off = 1; off < 64; off <<= 1) {
      float ov = __shfl_xor(bd, off);
      int os = __shfl_xor(bs2, off);
      if (ov < bd || (ov == bd && os < bs2)) { bd = ov; bs2 = os; }
    }
    if (l == 0) out[2 + R] = (float)bs2;
  }
}

// ---------------- K2: straight-through output + commitment loss ----------------
__global__ __launch_bounds__(256) void k2_output(
    const float* __restrict__ x, const float* __restrict__ cb,
    float* __restrict__ out, double* __restrict__ commit_partial) {
  __shared__ double r2[4];
  const int tid = threadIdx.x;
  const int bx = blockIdx.x;
  const int n = bx >> 9, c = bx & 511;
  const int p = tid * 4;

  const float* xr = x + ((size_t)n * C_ + c) * P_ + p;
  float4 xv = *(const float4*)xr;
  float xs[4] = {xv.x, xv.y, xv.z, xv.w};
  const float* idxf = out + 2 + n * P_ + p;
  float o[4];
  float acc = 0.f;
#pragma unroll
  for (int k = 0; k < 4; ++k) {
    int s = (int)idxf[k];
    float q = cb[(size_t)s * C_ + c];
    float t = __fsub_rn(q, xs[k]);
    o[k] = __fadd_rn(xs[k], t);
    float dd = __fsub_rn(xs[k], q);
    acc += dd * dd;
  }
  float* orow = out + 2 + N_ * P_ + ((size_t)n * C_ + c) * P_ + p;
  ((float2*)orow)[0] = make_float2(o[0], o[1]);
  ((float2*)orow)[1] = make_float2(o[2], o[3]);

  double dacc = (double)acc;
#pragma unroll
  for (int off = 32; off > 0; off >>= 1) dacc += __shfl_down(dacc, off);
  if ((tid & 63) == 0) r2[tid >> 6] = dacc;
  __syncthreads();
  if (tid == 0) commit_partial[bx] = r2[0] + r2[1] + r2[2] + r2[3];
}

// ---------------- K3: finalize scalars ----------------
__global__ __launch_bounds__(256) void k3_finalize(
    const double* __restrict__ pa, int na, const double* __restrict__ pb, int nb,
    float* __restrict__ out) {
  __shared__ double red[8];
  const int tid = threadIdx.x;
  double a = 0.0, b = 0.0;
  for (int i = tid; i < na; i += 256) a += pa[i];
  for (int i = tid; i < nb; i += 256) b += pb[i];
#pragma unroll
  for (int off = 32; off > 0; off >>= 1) {
    a += __shfl_down(a, off);
    b += __shfl_down(b, off);
  }
  if ((tid & 63) == 0) {
    red[(tid >> 6) * 2 + 0] = a;
    red[(tid >> 6) * 2 + 1] = b;
  }
  __syncthreads();
  if (tid == 0) {
    double A = red[0] + red[2] + red[4] + red[6];
    double B = red[1] + red[3] + red[5] + red[7];
    out[0] = (float)(A / ((double)N_ * (double)S_ * (double)P_));
    out[1] = (float)(B / ((double)N_ * (double)C_ * (double)P_));
  }
}

// ======================= round-2 fallback (small-ws path) =======================
#define TPW 8
#define KC 32
#define SC 64
#define KCF 48
__global__ __launch_bounds__(256) void k1_fallback(
    const float* __restrict__ x, const float* __restrict__ cb,
    float* __restrict__ out, double* __restrict__ cb_partial) {
  __shared__ float dval[TPW][KCF];
  __shared__ float x2f[TPW];
  __shared__ double redd[4];
  __shared__ float x_t[TPW][C_ + 4];
  __shared__ float cb_t[SC][KC + 4];
  __shared__ int cand_s[TPW][KCF];
  __shared__ _Float16 sc[S_][TPW];

  const int tid = threadIdx.x;
  const int bx = blockIdx.x;
  const int n = bx >> 7;
  const int p0 = (bx & 127) * TPW;

  const float* xn = x + (size_t)n * C_ * P_ + p0;
#pragma unroll
  for (int q = 0; q < 16; ++q) {
    int e = tid + 256 * q;
    int c = e >> 3, j = e & 7;
    x_t[j][c] = xn[(size_t)c * P_ + j];
  }
  __syncthreads();
  if (tid < TPW) {
    float acc = 0.f;
    for (int c = 0; c < C_; ++c)
      acc = __fadd_rn(acc, __fmul_rn(x_t[tid][c], x_t[tid][c]));
    x2f[tid] = acc;
  }
  const int j = tid & 7;
  const int sg = tid >> 3;
  for (int s0 = 0; s0 < S_; s0 += SC) {
    float acc0 = 0.f, acc1 = 0.f;
    for (int k0 = 0; k0 < C_; k0 += KC) {
      __syncthreads();
#pragma unroll
      for (int q = 0; q < 8; ++q) {
        int e = tid + 256 * q;
        int i = e >> 5, cc = e & 31;
        cb_t[i][cc] = cb[(size_t)(s0 + i) * C_ + k0 + cc];
      }
      __syncthreads();
      const float* xr = &x_t[j][k0];
#pragma unroll
      for (int cs = 0; cs < KC; cs += 4) {
        float4 xv = *(const float4*)(xr + cs);
        float4 a4 = *(const float4*)(&cb_t[sg][cs]);
        float4 b4 = *(const float4*)(&cb_t[sg + 32][cs]);
        acc0 += xv.x * a4.x + xv.y * a4.y + xv.z * a4.z + xv.w * a4.w;
        acc1 += xv.x * b4.x + xv.y * b4.y + xv.z * b4.z + xv.w * b4.w;
      }
    }
    sc[s0 + sg][j] = (_Float16)acc0;
    sc[s0 + sg + 32][j] = (_Float16)acc1;
  }
  __syncthreads();
  {
    const int g = tid >> 5, t = tid & 31;
    for (int pass = 0; pass < KCF; ++pass) {
      float bv = -1e30f;
      int bs = 0;
      for (int k = 0; k < 64; ++k) {
        int s = t + 32 * k;
        float vv = (float)sc[s][g];
        if (vv > bv) { bv = vv; bs = s; }
      }
#pragma unroll
      for (int off = 1; off < 32; off <<= 1) {
        float ov = __shfl_xor(bv, off);
        int os = __shfl_xor(bs, off);
        if (ov > bv || (ov == bv && os < bs)) { bv = ov; bs = os; }
      }
      if (t == 0) {
        cand_s[g][pass] = bs;
        sc[bs][g] = (_Float16)(-65504.f);
      }
      __syncthreads();
    }
  }
  for (int task = tid; task < TPW * KCF; task += 256) {
    int jj = task / KCF, r = task % KCF;
    int s = cand_s[jj][r];
    const float* row = cb + (size_t)s * C_;
    const float* xrw = &x_t[jj][0];
    float acc = 0.f;
    double c2d = 0.0;
    for (int c = 0; c < C_; c += 4) {
      float4 cv = *(const float4*)(row + c);
      acc = __fadd_rn(acc, __fmul_rn(xrw[c + 0], cv.x));
      acc = __fadd_rn(acc, __fmul_rn(xrw[c + 1], cv.y));
      acc = __fadd_rn(acc, __fmul_rn(xrw[c + 2], cv.z));
      acc = __fadd_rn(acc, __fmul_rn(xrw[c + 3], cv.w));
      c2d += (double)__fmul_rn(cv.x, cv.x);
      c2d += (double)__fmul_rn(cv.y, cv.y);
      c2d += (double)__fmul_rn(cv.z, cv.z);
      c2d += (double)__fmul_rn(cv.w, cv.w);
    }
    float c2s = (float)c2d;
    dval[jj][r] = __fsub_rn(__fadd_rn(x2f[jj], c2s), __fmul_rn(2.f, acc));
  }
  __syncthreads();
  double contrib = 0.0;
  for (int task = tid; task < TPW * KCF; task += 256) {
    int jj = task / KCF, r = task % KCF;
    float e = dval[jj][r];
    int s = cand_s[jj][r];
    int rank = 0;
    for (int r2 = 0; r2 < KCF; ++r2) {
      float e2 = dval[jj][r2];
      int s2 = cand_s[jj][r2];
      rank += (e2 < e || (e2 == e && s2 < s)) ? 1 : 0;
    }
    contrib += exp((double)(-rank)) * (double)e;
    if (rank == 0) out[2 + n * P_ + p0 + jj] = (float)s;
  }
  __syncthreads();
#pragma unroll
  for (int off = 32; off > 0; off >>= 1) contrib += __shfl_down(contrib, off);
  if ((tid & 63) == 0) redd[tid >> 6] = contrib;
  __syncthreads();
  if (tid == 0) cb_partial[bx] = redd[0] + redd[1] + redd[2] + redd[3];
}

extern "C" void kernel_launch(void* const* d_in, const int* in_sizes, int n_in,
                              void* d_out, int out_size, void* d_ws, size_t ws_size,
                              hipStream_t stream) {
  const float* x = (const float*)d_in[0];
  const float* cb = (const float*)d_in[1];
  float* out = (float*)d_out;
  char* ws = (char*)d_ws;

  if (ws_size >= WS_TOTAL) {
    unsigned short* xT = (unsigned short*)(ws + WS_XT);
    float* xTf = (float*)(ws + WS_XTF);
    unsigned short* cbT = (unsigned short*)(ws + WS_CBT);
    float* c2f = (float*)(ws + WS_C2F);
    float* x2ws = (float*)(ws + WS_X2);
    int* cnt = (int*)(ws + WS_CNT);
    float* candv = (float*)(ws + WS_CANDV);
    int* cands = (int*)(ws + WS_CANDS);
    double* rowpart = (double*)(ws + WS_ROWPART);
    double* commitp = (double*)(ws + WS_COMMIT);

    hipLaunchKernelGGL(k_cvt_cb, dim3(S_), dim3(64), 0, stream, cb, cbT, c2f);
    hipLaunchKernelGGL(k_x2, dim3(128), dim3(256), 0, stream, x, x2ws, cnt);
    hipLaunchKernelGGL(k_transpose_x, dim3(4096), dim3(256), 0, stream, x, xT, xTf);
    hipLaunchKernelGGL(k_gemm, dim3(4096), dim3(256), 0, stream,
                       xT, cbT, x2ws, candv, cands, cnt);
    hipLaunchKernelGGL(k_phase2, dim3(NR_ / 4), dim3(256), 0, stream,
                       cb, xTf, candv, cands, cnt, c2f, x2ws, out, rowpart);
    hipLaunchKernelGGL(k2_output, dim3(16384), dim3(256), 0, stream, x, cb, out, commitp);
    hipLaunchKernelGGL(k3_finalize, dim3(1), dim3(256), 0, stream,
                       rowpart, NR_, commitp, 16384, out);
  } else {
    double* cb_partial = (double*)d_ws;
    double* commitp = cb_partial + 4096;
    hipLaunchKernelGGL(k1_fallback, dim3(4096), dim3(256), 0, stream, x, cb, out, cb_partial);
    hipLaunchKernelGGL(k2_output, dim3(16384), dim3(256), 0, stream, x, cb, out, commitp);
    hipLaunchKernelGGL(k3_finalize, dim3(1), dim3(256), 0, stream,
                       cb_partial, 4096, commitp, 16384, out);
  }
}

// Round 5
// 462.984 us; speedup vs baseline: 9.4987x; 1.1667x over previous
//
#include <hip/hip_runtime.h>
#include <hip/hip_fp16.h>

#define N_ 32
#define C_ 512
#define P_ 1024
#define S_ 2048
#define NR_ (N_ * P_)   // 32768 rows
#define GUARD 6e-3f     // ~30 sigma of bf16-score diff noise; np-rescore set radius
#define TSIG 2.3f       // candidate threshold in row-sigma units

typedef __attribute__((ext_vector_type(8))) short sh8;
typedef __attribute__((ext_vector_type(4))) float fx4;

// ---- ws layout (bytes) ----
#define WS_XT       0ull            // ushort bf16 [32768][512] = 33554432
#define WS_XTF      33554432ull     // float [32768][512]       = 67108864
#define WS_CBT      100663296ull    // ushort bf16 [2048][512]  = 2097152
#define WS_C2F      102760448ull    // float [2048]             = 8192
#define WS_X2       102768640ull    // float [32768]            = 131072
#define WS_CNT      102899712ull    // int [32768]              = 131072
#define WS_CANDV    103030784ull    // float [32768][64]        = 8388608
#define WS_CANDS    111419392ull    // int [32768][64]          = 8388608
#define WS_ROWPART  119808000ull    // double [32768]           = 262144
#define WS_COMMIT   120070144ull    // double [16384]           = 131072
#define WS_TOTAL    120201216ull

#define TBLK 2048       // transpose blocks in k_prep (16 rows each)
#define CVTBLK 512      // cvt blocks in k_prep (4 cb rows each)

__device__ __forceinline__ unsigned short f2bf(float f) {
  union { float f; unsigned u; } x; x.f = f;
  unsigned r = x.u + 0x7fffu + ((x.u >> 16) & 1u);
  return (unsigned short)(r >> 16);
}

template <typename T>
__device__ __forceinline__ void load16_lds(const T* g, T* l) {
  __builtin_amdgcn_global_load_lds((const __attribute__((address_space(1))) void*)g,
                                   (__attribute__((address_space(3))) void*)l, 16, 0, 0);
}

// ---------------- k_prep: fused {transpose+cvt x, np x2 chain, cnt=0} + {cvt cb, c2} --
__global__ __launch_bounds__(256) void k_prep(const float* __restrict__ x,
                                              const float* __restrict__ cb,
                                              unsigned short* __restrict__ xT,
                                              float* __restrict__ xTf,
                                              unsigned short* __restrict__ cbT,
                                              float* __restrict__ c2f,
                                              float* __restrict__ x2ws,
                                              int* __restrict__ cnt) {
  __shared__ float tile[16][516];   // 33 KB; stride 516 -> 16B-aligned rows
  const int tid = threadIdx.x;
  const int bx = blockIdx.x;

  if (bx < TBLK) {
    // ---- transpose 16 p-rows x 512 c ----
    const int n = bx >> 6;
    const int p0 = (bx & 63) << 4;
    const float* xb = x + (size_t)n * (C_ * P_) + p0;
    const int pl = tid & 15, ch = tid >> 4;  // 16 c's per iteration
#pragma unroll 4
    for (int it = 0; it < 32; ++it) {
      int c = it * 16 + ch;
      tile[pl][c] = xb[(size_t)c * P_ + pl];
    }
    __syncthreads();

    // xTf (fp32 rows) + xT (bf16 rows), contiguous writes
#pragma unroll
    for (int it = 0; it < 8; ++it) {
      int idx = tid + 256 * it;          // 0..2047 float4s
      int row = idx >> 7, c4 = (idx & 127) << 2;
      float4 f = *(const float4*)&tile[row][c4];
      size_t R = (size_t)((n << 10) + p0 + row);
      *(float4*)(xTf + R * C_ + c4) = f;
      ushort4 o;
      o.x = f2bf(f.x); o.y = f2bf(f.y); o.z = f2bf(f.z); o.w = f2bf(f.w);
      *(ushort4*)(xT + R * C_ + c4) = o;
    }

    // np-exact x2: strict sequential fp32 chain over c (ascending), no FMA
    if (tid < 16) {
      float acc = 0.f;
      for (int c = 0; c < C_; ++c) {
        float t = tile[tid][c];
        acc = __fadd_rn(acc, __fmul_rn(t, t));
      }
      int R = (n << 10) + p0 + tid;
      x2ws[R] = acc;
      cnt[R] = 0;
    }
  } else {
    // ---- cvt codebook rows to bf16 + c2 (fp64 sum of fp32 squares -> fp32) ----
    const int s = (bx - TBLK) * 4 + (tid >> 6);
    const int l = tid & 63;
    const float* row = cb + (size_t)s * C_;
    double c2d = 0.0;
#pragma unroll
    for (int h = 0; h < 2; ++h) {
      int c = h * 256 + l * 4;
      float4 v = *(const float4*)(row + c);
      ushort4 o;
      o.x = f2bf(v.x); o.y = f2bf(v.y); o.z = f2bf(v.z); o.w = f2bf(v.w);
      *(ushort4*)(cbT + (size_t)s * C_ + c) = o;
      c2d += (double)__fmul_rn(v.x, v.x) + (double)__fmul_rn(v.y, v.y) +
             (double)__fmul_rn(v.z, v.z) + (double)__fmul_rn(v.w, v.w);
    }
#pragma unroll
    for (int off = 32; off > 0; off >>= 1) c2d += __shfl_down(c2d, off);
    if (l == 0) c2f[s] = (float)c2d;
  }
}

// ---------------- MFMA GEMM + threshold epilogue -> per-row candidate lists -------
// 128x128 tile, BK=64, 4 waves, XOR-swizzled LDS, global_load_lds 16B.
// Block swizzle: all 16 s-tiles of one m-tile land on the same XCD (bx%8).
__global__ __launch_bounds__(256, 4) void k_gemm(const unsigned short* __restrict__ xT,
                                                 const unsigned short* __restrict__ cbT,
                                                 const float* __restrict__ x2ws,
                                                 float* __restrict__ candv,
                                                 int* __restrict__ cands,
                                                 int* __restrict__ cnt) {
  __shared__ unsigned short As[128 * 64];  // 16 KB, chunk (m*8 + (k8 ^ (m&7)))
  __shared__ unsigned short Bs[128 * 64];
  __shared__ float t_lds[128];
  const int tid = threadIdx.x;
  const int w = tid >> 6, l = tid & 63;
  const int bx = blockIdx.x;
  // XCD-aware swizzle: xcd = bx&7 fixed per m-tile, s-tile = (bx>>3)&15
  const int m_tile = ((bx >> 7) << 3) + (bx & 7);
  const int s_tile = (bx >> 3) & 15;
  const int m0 = m_tile << 7, s0 = s_tile << 7;
  const int wm = (w & 1) << 6, wsf = (w >> 1) << 6;
  const int quad = l >> 4, lane15 = l & 15;

  if (tid < 128) t_lds[tid] = TSIG * __fsqrt_rn(x2ws[m0 + tid]) * (1.0f / 512.0f);

  size_t gA[4], gB[4];
  unsigned short *lA[4], *lB[4];
#pragma unroll
  for (int q = 0; q < 4; ++q) {
    int chunk = (q * 4 + w) * 64 + l;
    int m = chunk >> 3, k8s = chunk & 7;
    int k8 = k8s ^ (m & 7);
    gA[q] = (size_t)(m0 + m) * (C_ * 2) + (size_t)k8 * 16;
    gB[q] = (size_t)(s0 + m) * (C_ * 2) + (size_t)k8 * 16;
    lA[q] = As + (q * 4 + w) * 512;
    lB[q] = Bs + (q * 4 + w) * 512;
  }
  const char* xb = (const char*)xT;
  const char* cbb = (const char*)cbT;

  fx4 acc[4][4];
#pragma unroll
  for (int i = 0; i < 4; ++i)
#pragma unroll
    for (int j = 0; j < 4; ++j) acc[i][j] = (fx4){0.f, 0.f, 0.f, 0.f};

  for (int kk = 0; kk < 8; ++kk) {
#pragma unroll
    for (int q = 0; q < 4; ++q) {
      load16_lds((const unsigned short*)(xb + gA[q] + (size_t)kk * 128), lA[q]);
      load16_lds((const unsigned short*)(cbb + gB[q] + (size_t)kk * 128), lB[q]);
    }
    __syncthreads();
#pragma unroll
    for (int ks = 0; ks < 2; ++ks) {
      const int k8g = ks * 4 + quad;
      sh8 af[4], bf[4];
#pragma unroll
      for (int mi = 0; mi < 4; ++mi) {
        int m = wm + mi * 16 + lane15;
        af[mi] = *(const sh8*)(As + m * 64 + (k8g ^ (m & 7)) * 8);
      }
#pragma unroll
      for (int si = 0; si < 4; ++si) {
        int s = wsf + si * 16 + lane15;
        bf[si] = *(const sh8*)(Bs + s * 64 + (k8g ^ (s & 7)) * 8);
      }
#pragma unroll
      for (int mi = 0; mi < 4; ++mi)
#pragma unroll
        for (int si = 0; si < 4; ++si)
          acc[mi][si] = __builtin_amdgcn_mfma_f32_16x16x32_bf16(af[mi], bf[si], acc[mi][si], 0, 0, 0);
    }
    __syncthreads();
  }

  // Epilogue: segment-aggregated threshold appends + per-slab row-max guarantee.
  // C/D layout: row = wm+mi*16+quad*4+r, col = s0+wsf+si*16+lane15.
  const unsigned below = (1u << lane15) - 1u;
#pragma unroll
  for (int mi = 0; mi < 4; ++mi) {
#pragma unroll
    for (int r = 0; r < 4; ++r) {
      const int rowl = wm + mi * 16 + quad * 4 + r;
      const int rowg = m0 + rowl;
      const float t = t_lds[rowl];
      float v[4]; int scol[4]; bool hit[4];
      float vmax = -1e30f; int smax = 0;
#pragma unroll
      for (int si = 0; si < 4; ++si) {
        v[si] = acc[mi][si][r];
        scol[si] = s0 + wsf + si * 16 + lane15;
        hit[si] = v[si] >= t;
        if (v[si] > vmax) { vmax = v[si]; smax = scol[si]; }
      }
      int total = 0, myslot[4];
#pragma unroll
      for (int si = 0; si < 4; ++si) {
        unsigned long long b = __ballot(hit[si]);
        unsigned seg = (unsigned)((b >> (quad * 16)) & 0xFFFFull);
        myslot[si] = total + __popc(seg & below);
        total += __popc(seg);
      }
      // 16-lane segment max reduce (offsets < 16 stay in segment)
#pragma unroll
      for (int off = 1; off < 16; off <<= 1) {
        float ov = __shfl_xor(vmax, off);
        int os = __shfl_xor(smax, off);
        if (ov > vmax) { vmax = ov; smax = os; }
      }
      int base = 0;
      if (lane15 == 0) base = atomicAdd(&cnt[rowg], total > 0 ? total : 1);
      base = __shfl(base, quad * 16);
      if (total > 0) {
#pragma unroll
        for (int si = 0; si < 4; ++si) {
          if (hit[si]) {
            int slot = base + myslot[si];
            if (slot < 64) {
              candv[(size_t)rowg * 64 + slot] = v[si];
              cands[(size_t)rowg * 64 + slot] = scol[si];
            }
          }
        }
      } else if (lane15 == 0 && base < 64) {
        candv[(size_t)rowg * 64 + base] = vmax;
        cands[(size_t)rowg * 64 + base] = smax;
      }
    }
  }
}

// ---------------- phase 2: ranks/loss from d~, lazy np-fp32 rescore for argmin ----
__global__ __launch_bounds__(256, 4) void k_phase2(
    const float* __restrict__ cb, const float* __restrict__ xTf,
    const float* __restrict__ candvG, const int* __restrict__ candsG,
    const int* __restrict__ cntG, const float* __restrict__ c2f,
    const float* __restrict__ x2ws, float* __restrict__ out,
    double* __restrict__ rowpart) {
  __shared__ float xrow[4][C_];
  const int tid = threadIdx.x;
  const int w = tid >> 6, l = tid & 63;
  const int R = blockIdx.x * 4 + w;

  const int cnt = min(cntG[R], 64);
  const float x2f = x2ws[R];
  const bool act = l < cnt;
  float v = candvG[(size_t)R * 64 + l];
  int s = candsG[(size_t)R * 64 + l];
  v = act ? v : -1e30f;
  s = act ? s : 0x7fffffff;
  const int sIdx = act ? s : 0;
  const float dt = act
      ? __fsub_rn(__fadd_rn(x2f, c2f[sIdx]), __fmul_rn(2.f, v))
      : 1e30f;

  float M = v;
#pragma unroll
  for (int off = 1; off < 64; off <<= 1) M = fmaxf(M, __shfl_xor(M, off));

  int rank = 0;
  for (int k = 0; k < 64; ++k) {
    float dk = __shfl(dt, k);
    int sk = __shfl(s, k);
    rank += (dk < dt || (dk == dt && sk < s)) ? 1 : 0;
  }

  double contrib = act ? (double)__expf(-(float)rank) * (double)dt : 0.0;
#pragma unroll
  for (int off = 32; off > 0; off >>= 1) contrib += __shfl_down(contrib, off);
  if (l == 0) rowpart[R] = contrib;

  const bool near = act && (v >= M - GUARD);
  const unsigned long long bal = __ballot(near);
  const int nres = __popcll(bal);
  if (nres == 1) {
    int src = __ffsll(bal) - 1;
    int wins = __shfl(s, src);
    if (l == 0) out[2 + R] = (float)wins;
  } else {
#pragma unroll
    for (int k = 0; k < 2; ++k)
      *(float4*)&xrow[w][l * 8 + k * 4] = *(const float4*)(xTf + (size_t)R * C_ + l * 8 + k * 4);
    float d32 = 1e30f;
    if (near) {
      const float4* crow = (const float4*)(cb + (size_t)s * C_);
      float acc = 0.f;
#pragma unroll 8
      for (int i = 0; i < C_ / 4; ++i) {
        float4 cv = crow[i];
        float4 xv = *(const float4*)&xrow[w][i * 4];
        acc = __fadd_rn(acc, __fmul_rn(xv.x, cv.x));
        acc = __fadd_rn(acc, __fmul_rn(xv.y, cv.y));
        acc = __fadd_rn(acc, __fmul_rn(xv.z, cv.z));
        acc = __fadd_rn(acc, __fmul_rn(xv.w, cv.w));
      }
      d32 = __fsub_rn(__fadd_rn(x2f, c2f[s]), __fmul_rn(2.f, acc));
    }
    float bd = d32;
    int bs2 = near ? s : 0x7fffffff;
#pragma unroll
    for (int off = 1; off < 64; off <<= 1) {
      float ov = __shfl_xor(bd, off);
      int os = __shfl_xor(bs2, off);
      if (ov < bd || (ov == bd && os < bs2)) { bd = ov; bs2 = os; }
    }
    if (l == 0) out[2 + R] = (float)bs2;
  }
}

// ---------------- K2: straight-through output + commitment loss ----------------
__global__ __launch_bounds__(256) void k2_output(
    const float* __restrict__ x, const float* __restrict__ cb,
    float* __restrict__ out, double* __restrict__ commit_partial) {
  __shared__ double r2[4];
  const int tid = threadIdx.x;
  const int bx = blockIdx.x;
  const int n = bx >> 9, c = bx & 511;
  const int p = tid * 4;

  const float* xr = x + ((size_t)n * C_ + c) * P_ + p;
  float4 xv = *(const float4*)xr;
  float xs[4] = {xv.x, xv.y, xv.z, xv.w};
  const float* idxf = out + 2 + n * P_ + p;
  float o[4];
  float acc = 0.f;
#pragma unroll
  for (int k = 0; k < 4; ++k) {
    int s = (int)idxf[k];
    float q = cb[(size_t)s * C_ + c];
    float t = __fsub_rn(q, xs[k]);
    o[k] = __fadd_rn(xs[k], t);
    float dd = __fsub_rn(xs[k], q);
    acc += dd * dd;
  }
  float* orow = out + 2 + N_ * P_ + ((size_t)n * C_ + c) * P_ + p;
  ((float2*)orow)[0] = make_float2(o[0], o[1]);
  ((float2*)orow)[1] = make_float2(o[2], o[3]);

  double dacc = (double)acc;
#pragma unroll
  for (int off = 32; off > 0; off >>= 1) dacc += __shfl_down(dacc, off);
  if ((tid & 63) == 0) r2[tid >> 6] = dacc;
  __syncthreads();
  if (tid == 0) commit_partial[bx] = r2[0] + r2[1] + r2[2] + r2[3];
}

// ---------------- K3: finalize scalars ----------------
__global__ __launch_bounds__(256) void k3_finalize(
    const double* __restrict__ pa, int na, const double* __restrict__ pb, int nb,
    float* __restrict__ out) {
  __shared__ double red[8];
  const int tid = threadIdx.x;
  double a = 0.0, b = 0.0;
  for (int i = tid; i < na; i += 256) a += pa[i];
  for (int i = tid; i < nb; i += 256) b += pb[i];
#pragma unroll
  for (int off = 32; off > 0; off >>= 1) {
    a += __shfl_down(a, off);
    b += __shfl_down(b, off);
  }
  if ((tid & 63) == 0) {
    red[(tid >> 6) * 2 + 0] = a;
    red[(tid >> 6) * 2 + 1] = b;
  }
  __syncthreads();
  if (tid == 0) {
    double A = red[0] + red[2] + red[4] + red[6];
    double B = red[1] + red[3] + red[5] + red[7];
    out[0] = (float)(A / ((double)N_ * (double)S_ * (double)P_));
    out[1] = (float)(B / ((double)N_ * (double)C_ * (double)P_));
  }
}

// ======================= round-2 fallback (small-ws path) =======================
#define TPW 8
#define KC 32
#define SC 64
#define KCF 48
__global__ __launch_bounds__(256) void k1_fallback(
    const float* __restrict__ x, const float* __restrict__ cb,
    float* __restrict__ out, double* __restrict__ cb_partial) {
  __shared__ float dval[TPW][KCF];
  __shared__ float x2f[TPW];
  __shared__ double redd[4];
  __shared__ float x_t[TPW][C_ + 4];
  __shared__ float cb_t[SC][KC + 4];
  __shared__ int cand_s[TPW][KCF];
  __shared__ _Float16 sc[S_][TPW];

  const int tid = threadIdx.x;
  const int bx = blockIdx.x;
  const int n = bx >> 7;
  const int p0 = (bx & 127) * TPW;

  const float* xn = x + (size_t)n * C_ * P_ + p0;
#pragma unroll
  for (int q = 0; q < 16; ++q) {
    int e = tid + 256 * q;
    int c = e >> 3, j = e & 7;
    x_t[j][c] = xn[(size_t)c * P_ + j];
  }
  __syncthreads();
  if (tid < TPW) {
    float acc = 0.f;
    for (int c = 0; c < C_; ++c)
      acc = __fadd_rn(acc, __fmul_rn(x_t[tid][c], x_t[tid][c]));
    x2f[tid] = acc;
  }
  const int j = tid & 7;
  const int sg = tid >> 3;
  for (int s0 = 0; s0 < S_; s0 += SC) {
    float acc0 = 0.f, acc1 = 0.f;
    for (int k0 = 0; k0 < C_; k0 += KC) {
      __syncthreads();
#pragma unroll
      for (int q = 0; q < 8; ++q) {
        int e = tid + 256 * q;
        int i = e >> 5, cc = e & 31;
        cb_t[i][cc] = cb[(size_t)(s0 + i) * C_ + k0 + cc];
      }
      __syncthreads();
      const float* xr = &x_t[j][k0];
#pragma unroll
      for (int cs = 0; cs < KC; cs += 4) {
        float4 xv = *(const float4*)(xr + cs);
        float4 a4 = *(const float4*)(&cb_t[sg][cs]);
        float4 b4 = *(const float4*)(&cb_t[sg + 32][cs]);
        acc0 += xv.x * a4.x + xv.y * a4.y + xv.z * a4.z + xv.w * a4.w;
        acc1 += xv.x * b4.x + xv.y * b4.y + xv.z * b4.z + xv.w * b4.w;
      }
    }
    sc[s0 + sg][j] = (_Float16)acc0;
    sc[s0 + sg + 32][j] = (_Float16)acc1;
  }
  __syncthreads();
  {
    const int g = tid >> 5, t = tid & 31;
    for (int pass = 0; pass < KCF; ++pass) {
      float bv = -1e30f;
      int bs = 0;
      for (int k = 0; k < 64; ++k) {
        int s = t + 32 * k;
        float vv = (float)sc[s][g];
        if (vv > bv) { bv = vv; bs = s; }
      }
#pragma unroll
      for (int off = 1; off < 32; off <<= 1) {
        float ov = __shfl_xor(bv, off);
        int os = __shfl_xor(bs, off);
        if (ov > bv || (ov == bv && os < bs)) { bv = ov; bs = os; }
      }
      if (t == 0) {
        cand_s[g][pass] = bs;
        sc[bs][g] = (_Float16)(-65504.f);
      }
      __syncthreads();
    }
  }
  for (int task = tid; task < TPW * KCF; task += 256) {
    int jj = task / KCF, r = task % KCF;
    int s = cand_s[jj][r];
    const float* row = cb + (size_t)s * C_;
    const float* xrw = &x_t[jj][0];
    float acc = 0.f;
    double c2d = 0.0;
    for (int c = 0; c < C_; c += 4) {
      float4 cv = *(const float4*)(row + c);
      acc = __fadd_rn(acc, __fmul_rn(xrw[c + 0], cv.x));
      acc = __fadd_rn(acc, __fmul_rn(xrw[c + 1], cv.y));
      acc = __fadd_rn(acc, __fmul_rn(xrw[c + 2], cv.z));
      acc = __fadd_rn(acc, __fmul_rn(xrw[c + 3], cv.w));
      c2d += (double)__fmul_rn(cv.x, cv.x);
      c2d += (double)__fmul_rn(cv.y, cv.y);
      c2d += (double)__fmul_rn(cv.z, cv.z);
      c2d += (double)__fmul_rn(cv.w, cv.w);
    }
    float c2s = (float)c2d;
    dval[jj][r] = __fsub_rn(__fadd_rn(x2f[jj], c2s), __fmul_rn(2.f, acc));
  }
  __syncthreads();
  double contrib = 0.0;
  for (int task = tid; task < TPW * KCF; task += 256) {
    int jj = task / KCF, r = task % KCF;
    float e = dval[jj][r];
    int s = cand_s[jj][r];
    int rank = 0;
    for (int r2 = 0; r2 < KCF; ++r2) {
      float e2 = dval[jj][r2];
      int s2 = cand_s[jj][r2];
      rank += (e2 < e || (e2 == e && s2 < s)) ? 1 : 0;
    }
    contrib += exp((double)(-rank)) * (double)e;
    if (rank == 0) out[2 + n * P_ + p0 + jj] = (float)s;
  }
  __syncthreads();
#pragma unroll
  for (int off = 32; off > 0; off >>= 1) contrib += __shfl_down(contrib, off);
  if ((tid & 63) == 0) redd[tid >> 6] = contrib;
  __syncthreads();
  if (tid == 0) cb_partial[bx] = redd[0] + redd[1] + redd[2] + redd[3];
}

extern "C" void kernel_launch(void* const* d_in, const int* in_sizes, int n_in,
                              void* d_out, int out_size, void* d_ws, size_t ws_size,
                              hipStream_t stream) {
  const float* x = (const float*)d_in[0];
  const float* cb = (const float*)d_in[1];
  float* out = (float*)d_out;
  char* ws = (char*)d_ws;

  if (ws_size >= WS_TOTAL) {
    unsigned short* xT = (unsigned short*)(ws + WS_XT);
    float* xTf = (float*)(ws + WS_XTF);
    unsigned short* cbT = (unsigned short*)(ws + WS_CBT);
    float* c2f = (float*)(ws + WS_C2F);
    float* x2ws = (float*)(ws + WS_X2);
    int* cnt = (int*)(ws + WS_CNT);
    float* candv = (float*)(ws + WS_CANDV);
    int* cands = (int*)(ws + WS_CANDS);
    double* rowpart = (double*)(ws + WS_ROWPART);
    double* commitp = (double*)(ws + WS_COMMIT);

    hipLaunchKernelGGL(k_prep, dim3(TBLK + CVTBLK), dim3(256), 0, stream,
                       x, cb, xT, xTf, cbT, c2f, x2ws, cnt);
    hipLaunchKernelGGL(k_gemm, dim3(4096), dim3(256), 0, stream,
                       xT, cbT, x2ws, candv, cands, cnt);
    hipLaunchKernelGGL(k_phase2, dim3(NR_ / 4), dim3(256), 0, stream,
                       cb, xTf, candv, cands, cnt, c2f, x2ws, out, rowpart);
    hipLaunchKernelGGL(k2_output, dim3(16384), dim3(256), 0, stream, x, cb, out, commitp);
    hipLaunchKernelGGL(k3_finalize, dim3(1), dim3(256), 0, stream,
                       rowpart, NR_, commitp, 16384, out);
  } else {
    double* cb_partial = (double*)d_ws;
    double* commitp = cb_partial + 4096;
    hipLaunchKernelGGL(k1_fallback, dim3(4096), dim3(256), 0, stream, x, cb, out, cb_partial);
    hipLaunchKernelGGL(k2_output, dim3(16384), dim3(256), 0, stream, x, cb, out, commitp);
    hipLaunchKernelGGL(k3_finalize, dim3(1), dim3(256), 0, stream,
                       cb_partial, 4096, commitp, 16384, out);
  }
}